// Round 5
// baseline (49824.750 us; speedup 1.0000x reference)
//
#include <hip/hip_runtime.h>
#include <hip/hip_bf16.h>
#include <math.h>

#define B_  64
#define T_  512
#define I_  512
#define H_  1024
#define G4_ 4096
#define O_  512
#define TC_ 64             // time chunk
#define NCH (T_ / TC_)     // 8
#define NWG_P 256
#define WG_PER_GROUP 32    // 8 barrier groups of 32 WGs

typedef short  s16x8 __attribute__((ext_vector_type(8)));
typedef float  fx4   __attribute__((ext_vector_type(4)));
typedef float  fx8   __attribute__((ext_vector_type(8)));
typedef unsigned short u16;
typedef u16    u16x4 __attribute__((ext_vector_type(4)));

__device__ __forceinline__ u16 f2bf(float f){
  unsigned u = __float_as_uint(f);
  unsigned r = u + 0x7fffu + ((u >> 16) & 1u);   // RNE
  return (u16)(r >> 16);
}
__device__ __forceinline__ float bf2f(u16 s){ return __uint_as_float(((unsigned)s) << 16); }
__device__ __forceinline__ float sigm(float x){ return 1.0f / (1.0f + __expf(-x)); }
__device__ __forceinline__ float tanh_(float x){
  float ax = fabsf(x);
  float e  = __expf(2.0f * ax);
  float r  = 1.0f - 2.0f / (e + 1.0f);
  return copysignf(r, x);
}
__device__ __forceinline__ fx4 mfma(s16x8 a, s16x8 b, fx4 c){
  return __builtin_amdgcn_mfma_f32_16x16x32_bf16(a, b, c, 0, 0, 0);
}

// ---------------- prep kernels ----------------
__global__ void cvt_hilo(const float* __restrict__ src, u16* __restrict__ hi,
                         u16* __restrict__ lo, int n4){
  int i      = blockIdx.x * blockDim.x + threadIdx.x;
  int stride = gridDim.x * blockDim.x;
  for (; i < n4; i += stride){
    fx4 v = ((const fx4*)src)[i];
    u16x4 h, l;
    #pragma unroll
    for (int k = 0; k < 4; ++k){
      u16 hh = f2bf(v[k]);
      h[k] = hh;
      l[k] = f2bf(v[k] - bf2f(hh));
    }
    ((u16x4*)hi)[i] = h;
    ((u16x4*)lo)[i] = l;
  }
}

__global__ void vadd(const float* __restrict__ a, const float* __restrict__ b,
                     float* __restrict__ o, int n){
  int i = blockIdx.x * blockDim.x + threadIdx.x;
  if (i < n) o[i] = a[i] + b[i];
}

// zero: cst1/cst2, slice-0 of the 4 archive arrays, barrier state
__global__ void zero_init(float* cst1, float* cst2,
                          u16* a0, u16* a1, u16* a2, u16* a3, unsigned* bar){
  int i = blockIdx.x * blockDim.x + threadIdx.x;
  const int n = B_ * H_;
  if (i < n){
    cst1[i] = 0.0f; cst2[i] = 0.0f;
    const size_t off = ((size_t)(i >> 10) * (TC_ + 1)) * H_ + (i & 1023);
    a0[off] = 0; a1[off] = 0; a2[off] = 0; a3[off] = 0;
  }
  if (i < 2048) bar[i] = 0u;
}

// ---------------- bulk GEMM (split-bf16, 128x64 tile) ----------------
// Row r = tl*64 + b. AMODE 0: A = fp32 x at [b][c0+tl][KD].
// AMODE 1: A = hi/lo bf16 archive at [b*(TC_+1) + tl + 1][KD]  (slice 0 = carry).
// OMODE 0: xp out[((tl*4+g)*H + j)*64 + b];  OMODE 1: out[(b*T_+c0+tl)*N + n].
template<int KD, int AMODE, int OMODE>
__global__ __launch_bounds__(256)
void gemmX(const float* __restrict__ Af,
           const u16* __restrict__ Ah, const u16* __restrict__ Al,
           const u16* __restrict__ Bh, const u16* __restrict__ Bl,
           const float* __restrict__ bias,
           float* __restrict__ out, int N, int c0)
{
  __shared__ float xt[(OMODE == 0) ? 64 * 130 : 4];
  const int lane = threadIdx.x & 63;
  const int wv   = threadIdx.x >> 6;
  const int l15  = lane & 15;
  const int lhi  = lane >> 4;
  const int koff = lhi * 8;
  const int mb   = blockIdx.x * 128;
  const int nb   = blockIdx.y * 64;
  const int r0   = mb + wv * 32 + l15;

  fx4 acc[2][4] = {};
  for (int kt = 0; kt < KD / 32; ++kt){
    const int kb = kt * 32 + koff;
    s16x8 ah[2], al[2];
    #pragma unroll
    for (int mi = 0; mi < 2; ++mi){
      const int r  = r0 + mi * 16;
      const int b  = r & 63;
      const int tl = r >> 6;
      if (AMODE == 0){
        const float* p = Af + ((size_t)b * T_ + c0 + tl) * KD + kb;
        fx8 v = *reinterpret_cast<const fx8*>(p);
        #pragma unroll
        for (int i = 0; i < 8; ++i){
          u16 h = f2bf(v[i]);
          ah[mi][i] = (short)h;
          al[mi][i] = (short)f2bf(v[i] - bf2f(h));
        }
      } else {
        const size_t ao = ((size_t)b * (TC_ + 1) + tl + 1) * KD + kb;
        ah[mi] = *reinterpret_cast<const s16x8*>(Ah + ao);
        al[mi] = *reinterpret_cast<const s16x8*>(Al + ao);
      }
    }
    #pragma unroll
    for (int c = 0; c < 4; ++c){
      const size_t wo = (size_t)(nb + c * 16 + l15) * KD + kb;
      s16x8 bh = *reinterpret_cast<const s16x8*>(Bh + wo);
      s16x8 bl = *reinterpret_cast<const s16x8*>(Bl + wo);
      #pragma unroll
      for (int mi = 0; mi < 2; ++mi){
        acc[mi][c] = mfma(ah[mi], bh, acc[mi][c]);
        acc[mi][c] = mfma(ah[mi], bl, acc[mi][c]);
        acc[mi][c] = mfma(al[mi], bh, acc[mi][c]);
      }
    }
  }

  if (OMODE == 0){
    #pragma unroll
    for (int c = 0; c < 4; ++c){
      const int nloc = c * 16 + l15;
      const float bv = bias[nb + nloc];
      #pragma unroll
      for (int mi = 0; mi < 2; ++mi)
        #pragma unroll
        for (int r = 0; r < 4; ++r)
          xt[nloc * 130 + wv * 32 + mi * 16 + lhi * 4 + r] = acc[mi][c][r] + bv;
    }
    __syncthreads();
    const int mloc = threadIdx.x & 127;
    const int b    = mloc & 63;
    const int tl   = blockIdx.x * 2 + (mloc >> 6);
    #pragma unroll
    for (int it = 0; it < 32; ++it){
      const int nloc = (threadIdx.x >> 7) + it * 2;
      const int n = nb + nloc;
      const int g = n >> 10;
      const int j = n & 1023;
      out[((size_t)(tl * 4 + g) * H_ + j) * 64 + b] = xt[nloc * 130 + mloc];
    }
  } else {
    #pragma unroll
    for (int c = 0; c < 4; ++c){
      const int n = nb + c * 16 + l15;
      const float bv = bias[n];
      #pragma unroll
      for (int mi = 0; mi < 2; ++mi)
        #pragma unroll
        for (int r = 0; r < 4; ++r){
          const int m  = mb + wv * 32 + mi * 16 + lhi * 4 + r;
          const int b  = m & 63;
          const int tl = m >> 6;
          out[((size_t)b * T_ + c0 + tl) * (size_t)N + n] = acc[mi][c][r] + bv;
        }
    }
  }
}

// ---------------- two-level grid barrier (hand-rolled, agent scope) ----------------
// bar layout (unsigned, stride-64 lines): cnt[g]=bar[g*64], gcnt=bar[512],
// gep=bar[576], grel[g]=bar[(10+g)*64]. Called by tid==0 only.
__device__ __forceinline__ void grid_barrier(unsigned* bar, int gid, unsigned ep){
  unsigned n = __hip_atomic_fetch_add(&bar[gid * 64], 1u, __ATOMIC_ACQ_REL,
                                      __HIP_MEMORY_SCOPE_AGENT);
  if (n == WG_PER_GROUP - 1){
    __hip_atomic_store(&bar[gid * 64], 0u, __ATOMIC_RELAXED, __HIP_MEMORY_SCOPE_AGENT);
    unsigned g = __hip_atomic_fetch_add(&bar[8 * 64], 1u, __ATOMIC_ACQ_REL,
                                        __HIP_MEMORY_SCOPE_AGENT);
    if (g == (NWG_P / WG_PER_GROUP) - 1){
      __hip_atomic_store(&bar[8 * 64], 0u, __ATOMIC_RELAXED, __HIP_MEMORY_SCOPE_AGENT);
      __hip_atomic_store(&bar[9 * 64], ep, __ATOMIC_RELEASE, __HIP_MEMORY_SCOPE_AGENT);
    } else {
      while (__hip_atomic_load(&bar[9 * 64], __ATOMIC_ACQUIRE,
                               __HIP_MEMORY_SCOPE_AGENT) != ep)
        __builtin_amdgcn_s_sleep(2);
    }
    __hip_atomic_store(&bar[(10 + gid) * 64], ep, __ATOMIC_RELEASE,
                       __HIP_MEMORY_SCOPE_AGENT);
  } else {
    while (__hip_atomic_load(&bar[(10 + gid) * 64], __ATOMIC_ACQUIRE,
                             __HIP_MEMORY_SCOPE_AGENT) != ep)
      __builtin_amdgcn_s_sleep(2);
  }
}

// ---------------- persistent LSTM chunk (TC_ steps, one layer) ----------------
// 256 WGs x 512 thr, cooperative (co-resident). WG owns 4 hidden units (16 gate
// cols); 8 waves K-split K=1024; Whh frags register-resident for all TC_ steps;
// c-state register-resident; h state = archive slices (slice 0 = carry-in,
// written again at tl==TC_-1 for the next chunk).
__global__ __launch_bounds__(512)
void lstm_pers(const u16* __restrict__ Wh, const u16* __restrict__ Wl,
               const float* __restrict__ xp,     // [TC_][4][H][B] fp32 (bias incl.)
               float* __restrict__ cst,          // [H][B]
               u16* __restrict__ hah, u16* __restrict__ hal,  // [B][TC_+1][H]
               unsigned* bar, unsigned ep0)
{
  __shared__ float red[64 * 129];
  const int tid  = threadIdx.x;
  const int lane = tid & 63;
  const int wv   = tid >> 6;
  const int l15  = lane & 15;
  const int lhi  = lane >> 4;
  const int koff = lhi * 8;
  const int jb4  = blockIdx.x * 4;
  const int wrow = (l15 >> 2) * H_ + jb4 + (l15 & 3);
  const int gid  = blockIdx.x >> 5;
  const int kb0  = wv * 128 + koff;

  // Whh fragments -> registers (reused all TC_ steps)
  s16x8 wfh[4], wfl[4];
  #pragma unroll
  for (int s = 0; s < 4; ++s){
    const size_t wo = (size_t)wrow * H_ + kb0 + s * 32;
    wfh[s] = *reinterpret_cast<const s16x8*>(Wh + wo);
    wfl[s] = *reinterpret_cast<const s16x8*>(Wl + wo);
  }

  const int em = tid & 63;
  const int eu = tid >> 6;              // valid when tid<256
  const int ej = jb4 + eu;
  float cv = 0.0f;
  if (tid < 256) cv = cst[ej * B_ + em];

  for (int tl = 0; tl < TC_; ++tl){
    // prefetch gate inputs (coalesced over b) while GEMM runs
    float xpv0 = 0, xpv1 = 0, xpv2 = 0, xpv3 = 0;
    if (tid < 256){
      const float* xr = xp + ((size_t)(tl * 4) * H_ + ej) * 64 + em;
      xpv0 = xr[0];
      xpv1 = xr[(size_t)H_ * 64];
      xpv2 = xr[(size_t)2 * H_ * 64];
      xpv3 = xr[(size_t)3 * H_ * 64];
    }

    fx4 acc[4] = {};
    #pragma unroll
    for (int s = 0; s < 4; ++s){
      const int kb = kb0 + s * 32;
      #pragma unroll
      for (int mt = 0; mt < 4; ++mt){
        const size_t ho = ((size_t)(mt * 16 + l15) * (TC_ + 1) + tl) * H_ + kb;
        s16x8 ah = *reinterpret_cast<const s16x8*>(hah + ho);
        s16x8 al = *reinterpret_cast<const s16x8*>(hal + ho);
        acc[mt] = mfma(ah, wfh[s], acc[mt]);
        acc[mt] = mfma(ah, wfl[s], acc[mt]);
        acc[mt] = mfma(al, wfh[s], acc[mt]);
      }
    }

    #pragma unroll
    for (int mt = 0; mt < 4; ++mt)
      #pragma unroll
      for (int r = 0; r < 4; ++r)
        red[(mt * 16 + lhi * 4 + r) * 129 + l15 * 8 + wv] = acc[mt][r];
    __syncthreads();

    if (tid < 256){
      float g[4];
      #pragma unroll
      for (int gi = 0; gi < 4; ++gi){
        const float* rp = red + em * 129 + (gi * 4 + eu) * 8;
        g[gi] = ((rp[0] + rp[1]) + (rp[2] + rp[3])) + ((rp[4] + rp[5]) + (rp[6] + rp[7]));
      }
      float iv = sigm (g[0] + xpv0);
      float fv = sigm (g[1] + xpv1);
      float gv = tanh_(g[2] + xpv2);
      float ov = sigm (g[3] + xpv3);
      float cn = fv * cv + iv * gv;
      float hv = ov * tanh_(cn);
      cv = cn;
      u16 hh = f2bf(hv);
      u16 hl = f2bf(hv - bf2f(hh));
      const size_t ai = ((size_t)em * (TC_ + 1) + tl + 1) * H_ + ej;
      hah[ai] = hh;
      hal[ai] = hl;
      if (tl == TC_ - 1){                       // carry for next chunk
        const size_t a0 = ((size_t)em * (TC_ + 1)) * H_ + ej;
        hah[a0] = hh;
        hal[a0] = hl;
      }
    }
    __syncthreads();                            // all stores in L2 before signal
    if (tid == 0) grid_barrier(bar, gid, ep0 + tl + 1);
    __syncthreads();
  }
  if (tid < 256) cst[ej * B_ + em] = cv;
}

// ---------------- host launch ----------------
extern "C" void kernel_launch(void* const* d_in, const int* in_sizes, int n_in,
                              void* d_out, int out_size, void* d_ws, size_t ws_size,
                              hipStream_t stream)
{
  const float* x    = (const float*)d_in[0];
  const float* Wih1 = (const float*)d_in[1];
  const float* Whh1 = (const float*)d_in[2];
  const float* bih1 = (const float*)d_in[3];
  const float* bhh1 = (const float*)d_in[4];
  const float* Wih2 = (const float*)d_in[5];
  const float* Whh2 = (const float*)d_in[6];
  const float* bih2 = (const float*)d_in[7];
  const float* bhh2 = (const float*)d_in[8];
  const float* fcW  = (const float*)d_in[9];
  const float* fcb  = (const float*)d_in[10];
  float* out = (float*)d_out;
  (void)in_sizes; (void)n_in; (void)out_size; (void)ws_size;

  char* base = (char*)d_ws;
  size_t off = 0;
  auto alloc = [&](size_t bytes) -> void* {
    void* p = base + off;
    off = (off + bytes + 255) & ~(size_t)255;
    return p;
  };
  u16* Wih1_hi = (u16*)alloc((size_t)G4_ * I_ * 2);
  u16* Wih1_lo = (u16*)alloc((size_t)G4_ * I_ * 2);
  u16* Whh1_hi = (u16*)alloc((size_t)G4_ * H_ * 2);
  u16* Whh1_lo = (u16*)alloc((size_t)G4_ * H_ * 2);
  u16* Wih2_hi = (u16*)alloc((size_t)G4_ * H_ * 2);
  u16* Wih2_lo = (u16*)alloc((size_t)G4_ * H_ * 2);
  u16* Whh2_hi = (u16*)alloc((size_t)G4_ * H_ * 2);
  u16* Whh2_lo = (u16*)alloc((size_t)G4_ * H_ * 2);
  u16* fcW_hi  = (u16*)alloc((size_t)O_ * H_ * 2);
  u16* fcW_lo  = (u16*)alloc((size_t)O_ * H_ * 2);
  float* bsum1 = (float*)alloc((size_t)G4_ * 4);
  float* bsum2 = (float*)alloc((size_t)G4_ * 4);
  float* cst1  = (float*)alloc((size_t)B_ * H_ * 4);
  float* cst2  = (float*)alloc((size_t)B_ * H_ * 4);
  u16* h1s_hi = (u16*)alloc((size_t)B_ * (TC_ + 1) * H_ * 2);
  u16* h1s_lo = (u16*)alloc((size_t)B_ * (TC_ + 1) * H_ * 2);
  u16* h2s_hi = (u16*)alloc((size_t)B_ * (TC_ + 1) * H_ * 2);
  u16* h2s_lo = (u16*)alloc((size_t)B_ * (TC_ + 1) * H_ * 2);
  float* xp1  = (float*)alloc((size_t)TC_ * G4_ * B_ * 4);  // 64 MB
  float* xp2  = (float*)alloc((size_t)TC_ * G4_ * B_ * 4);  // 64 MB
  unsigned* bar = (unsigned*)alloc(2048 * 4);

  // ---- prep ----
  cvt_hilo<<<512, 256, 0, stream>>>(Wih1, Wih1_hi, Wih1_lo, G4_ * I_ / 4);
  cvt_hilo<<<512, 256, 0, stream>>>(Whh1, Whh1_hi, Whh1_lo, G4_ * H_ / 4);
  cvt_hilo<<<512, 256, 0, stream>>>(Wih2, Wih2_hi, Wih2_lo, G4_ * H_ / 4);
  cvt_hilo<<<512, 256, 0, stream>>>(Whh2, Whh2_hi, Whh2_lo, G4_ * H_ / 4);
  cvt_hilo<<<256, 256, 0, stream>>>(fcW,  fcW_hi,  fcW_lo,  O_ * H_ / 4);
  vadd<<<16, 256, 0, stream>>>(bih1, bhh1, bsum1, G4_);
  vadd<<<16, 256, 0, stream>>>(bih2, bhh2, bsum2, G4_);
  zero_init<<<256, 256, 0, stream>>>(cst1, cst2, h1s_hi, h1s_lo, h2s_hi, h2s_lo, bar);

  const dim3 gX(32, 64);   // M=4096/128, N=4096/64
  const dim3 gF(32, 8);

  unsigned ep = 0;
  for (int c = 0; c < NCH; ++c){
    const int c0 = c * TC_;
    gemmX<I_, 0, 0><<<gX, 256, 0, stream>>>(
        x, nullptr, nullptr, Wih1_hi, Wih1_lo, bsum1, xp1, G4_, c0);
    {
      void* args[] = { (void*)&Whh1_hi, (void*)&Whh1_lo, (void*)&xp1, (void*)&cst1,
                       (void*)&h1s_hi, (void*)&h1s_lo, (void*)&bar, (void*)&ep };
      hipLaunchCooperativeKernel((const void*)lstm_pers, dim3(NWG_P), dim3(512),
                                 args, 0, stream);
      ep += TC_;
    }
    gemmX<H_, 1, 0><<<gX, 256, 0, stream>>>(
        nullptr, h1s_hi, h1s_lo, Wih2_hi, Wih2_lo, bsum2, xp2, G4_, c0);
    {
      void* args[] = { (void*)&Whh2_hi, (void*)&Whh2_lo, (void*)&xp2, (void*)&cst2,
                       (void*)&h2s_hi, (void*)&h2s_lo, (void*)&bar, (void*)&ep };
      hipLaunchCooperativeKernel((const void*)lstm_pers, dim3(NWG_P), dim3(512),
                                 args, 0, stream);
      ep += TC_;
    }
    gemmX<H_, 1, 1><<<gF, 256, 0, stream>>>(
        nullptr, h2s_hi, h2s_lo, fcW_hi, fcW_lo, fcb, out, O_, c0);
  }
}

// Round 6
// 15140.875 us; speedup vs baseline: 3.2907x; 3.2907x over previous
//
#include <hip/hip_runtime.h>
#include <hip/hip_bf16.h>
#include <math.h>

#define B_  64
#define T_  512
#define I_  512
#define H_  1024
#define G4_ 4096
#define O_  512
#define TC_ 64             // time chunk
#define NCH (T_ / TC_)     // 8

typedef short  s16x8 __attribute__((ext_vector_type(8)));
typedef float  fx4   __attribute__((ext_vector_type(4)));
typedef float  fx8   __attribute__((ext_vector_type(8)));
typedef unsigned short u16;
typedef u16    u16x4 __attribute__((ext_vector_type(4)));

__device__ __forceinline__ u16 f2bf(float f){
  unsigned u = __float_as_uint(f);
  unsigned r = u + 0x7fffu + ((u >> 16) & 1u);   // RNE
  return (u16)(r >> 16);
}
__device__ __forceinline__ float bf2f(u16 s){ return __uint_as_float(((unsigned)s) << 16); }
__device__ __forceinline__ float sigm(float x){ return 1.0f / (1.0f + __expf(-x)); }
__device__ __forceinline__ float tanh_(float x){
  float ax = fabsf(x);
  float e  = __expf(2.0f * ax);
  float r  = 1.0f - 2.0f / (e + 1.0f);
  return copysignf(r, x);
}
__device__ __forceinline__ fx4 mfma(s16x8 a, s16x8 b, fx4 c){
  return __builtin_amdgcn_mfma_f32_16x16x32_bf16(a, b, c, 0, 0, 0);
}

// ---------------- prep kernels ----------------
__global__ void cvt_hilo(const float* __restrict__ src, u16* __restrict__ hi,
                         u16* __restrict__ lo, int n4){
  int i      = blockIdx.x * blockDim.x + threadIdx.x;
  int stride = gridDim.x * blockDim.x;
  for (; i < n4; i += stride){
    fx4 v = ((const fx4*)src)[i];
    u16x4 h, l;
    #pragma unroll
    for (int k = 0; k < 4; ++k){
      u16 hh = f2bf(v[k]);
      h[k] = hh;
      l[k] = f2bf(v[k] - bf2f(hh));
    }
    ((u16x4*)hi)[i] = h;
    ((u16x4*)lo)[i] = l;
  }
}

__global__ void vadd(const float* __restrict__ a, const float* __restrict__ b,
                     float* __restrict__ o, int n){
  int i = blockIdx.x * blockDim.x + threadIdx.x;
  if (i < n) o[i] = a[i] + b[i];
}

// ---------------- bulk GEMM (split-bf16, 128x64 tile) ----------------
// Row r = tl*64 + b. AMODE 0: A = fp32 x at [b][c0+tl][KD]; AMODE 1: hi/lo [b*TC_+tl][KD].
// OMODE 0: xp out[((tl*4+g)*H + j)*64 + b];  OMODE 1: out[(b*T_+c0+tl)*N + n].
template<int KD, int AMODE, int OMODE>
__global__ __launch_bounds__(256)
void gemmX(const float* __restrict__ Af,
           const u16* __restrict__ Ah, const u16* __restrict__ Al,
           const u16* __restrict__ Bh, const u16* __restrict__ Bl,
           const float* __restrict__ bias,
           float* __restrict__ out, int N, int c0)
{
  __shared__ float xt[(OMODE == 0) ? 64 * 130 : 4];
  const int lane = threadIdx.x & 63;
  const int wv   = threadIdx.x >> 6;
  const int l15  = lane & 15;
  const int lhi  = lane >> 4;
  const int koff = lhi * 8;
  const int mb   = blockIdx.x * 128;
  const int nb   = blockIdx.y * 64;
  const int r0   = mb + wv * 32 + l15;

  fx4 acc[2][4] = {};
  for (int kt = 0; kt < KD / 32; ++kt){
    const int kb = kt * 32 + koff;
    s16x8 ah[2], al[2];
    #pragma unroll
    for (int mi = 0; mi < 2; ++mi){
      const int r  = r0 + mi * 16;
      const int b  = r & 63;
      const int tl = r >> 6;
      if (AMODE == 0){
        const float* p = Af + ((size_t)b * T_ + c0 + tl) * KD + kb;
        fx8 v = *reinterpret_cast<const fx8*>(p);
        #pragma unroll
        for (int i = 0; i < 8; ++i){
          u16 h = f2bf(v[i]);
          ah[mi][i] = (short)h;
          al[mi][i] = (short)f2bf(v[i] - bf2f(h));
        }
      } else {
        const size_t ao = ((size_t)b * TC_ + tl) * KD + kb;
        ah[mi] = *reinterpret_cast<const s16x8*>(Ah + ao);
        al[mi] = *reinterpret_cast<const s16x8*>(Al + ao);
      }
    }
    #pragma unroll
    for (int c = 0; c < 4; ++c){
      const size_t wo = (size_t)(nb + c * 16 + l15) * KD + kb;
      s16x8 bh = *reinterpret_cast<const s16x8*>(Bh + wo);
      s16x8 bl = *reinterpret_cast<const s16x8*>(Bl + wo);
      #pragma unroll
      for (int mi = 0; mi < 2; ++mi){
        acc[mi][c] = mfma(ah[mi], bh, acc[mi][c]);
        acc[mi][c] = mfma(ah[mi], bl, acc[mi][c]);
        acc[mi][c] = mfma(al[mi], bh, acc[mi][c]);
      }
    }
  }

  if (OMODE == 0){
    #pragma unroll
    for (int c = 0; c < 4; ++c){
      const int nloc = c * 16 + l15;
      const float bv = bias[nb + nloc];
      #pragma unroll
      for (int mi = 0; mi < 2; ++mi)
        #pragma unroll
        for (int r = 0; r < 4; ++r)
          xt[nloc * 130 + wv * 32 + mi * 16 + lhi * 4 + r] = acc[mi][c][r] + bv;
    }
    __syncthreads();
    const int mloc = threadIdx.x & 127;
    const int b    = mloc & 63;
    const int tl   = blockIdx.x * 2 + (mloc >> 6);
    #pragma unroll
    for (int it = 0; it < 32; ++it){
      const int nloc = (threadIdx.x >> 7) + it * 2;
      const int n = nb + nloc;
      const int g = n >> 10;
      const int j = n & 1023;
      out[((size_t)(tl * 4 + g) * H_ + j) * 64 + b] = xt[nloc * 130 + mloc];
    }
  } else {
    #pragma unroll
    for (int c = 0; c < 4; ++c){
      const int n = nb + c * 16 + l15;
      const float bv = bias[n];
      #pragma unroll
      for (int mi = 0; mi < 2; ++mi)
        #pragma unroll
        for (int r = 0; r < 4; ++r){
          const int m  = mb + wv * 32 + mi * 16 + lhi * 4 + r;
          const int b  = m & 63;
          const int tl = m >> 6;
          out[((size_t)b * T_ + c0 + tl) * (size_t)N + n] = acc[mi][c][r] + bv;
        }
    }
  }
}

// ---------------- dual-layer pipelined LSTM step (U=8, CT=2) ----------------
// mode bit0: L1 active, bit1: L2 active. mode==3: grid=256, blocks 0-127=L1,
// 128-255=L2. WG owns 8 hidden units = 32 gate-cols = 2 MFMA col-tiles:
// ct0 = gates {i,f}, ct1 = gates {g,o} for units jb8..jb8+7. 8 waves K-split
// K=1024 into 128 each; each wave loads A-frags ONCE per k-step and feeds both
// col-tiles (halves the h-broadcast vs CT=1). Cross-wave reduce in two LDS
// phases through one 33 KB buffer; epilogue = one thread per (b, unit).
__global__ __launch_bounds__(512)
void lstm_step_dual(int mode, int tl,
    const u16* __restrict__ W1h, const u16* __restrict__ W1l,
    const float* __restrict__ xp1, float* __restrict__ cst1,
    const u16* __restrict__ rh1, const u16* __restrict__ rl1,
    u16* __restrict__ nh1, u16* __restrict__ nl1,
    u16* __restrict__ ha1h, u16* __restrict__ ha1l,
    const u16* __restrict__ W2h, const u16* __restrict__ W2l,
    const float* __restrict__ xp2, float* __restrict__ cst2,
    const u16* __restrict__ rh2, const u16* __restrict__ rl2,
    u16* __restrict__ nh2, u16* __restrict__ nl2,
    u16* __restrict__ ha2h, u16* __restrict__ ha2l)
{
  __shared__ float red[64 * 129];

  int part, bx;
  if (mode == 3){ part = blockIdx.x >> 7; bx = blockIdx.x & 127; }
  else          { part = mode - 1;        bx = blockIdx.x; }

  const u16*   Wh  = part ? W2h  : W1h;
  const u16*   Wl  = part ? W2l  : W1l;
  const float* xp  = part ? xp2  : xp1;
  float*       cst = part ? cst2 : cst1;
  const u16*   rh  = part ? rh2  : rh1;
  const u16*   rl  = part ? rl2  : rl1;
  u16*         nh  = part ? nh2  : nh1;
  u16*         nl  = part ? nl2  : nl1;
  u16*         hah = part ? ha2h : ha1h;
  u16*         hal = part ? ha2l : ha1l;

  const int tid  = threadIdx.x;
  const int lane = tid & 63;
  const int wv   = tid >> 6;
  const int l15  = lane & 15;
  const int lhi  = lane >> 4;
  const int koff = lhi * 8;
  const int jb8  = bx * 8;

  // B cols: ct0 -> gate = l15>>3 (i,f), ct1 -> gate = 2+(l15>>3) (g,o); unit = l15&7
  const int wrow0 = ((l15 >> 3)    ) * H_ + jb8 + (l15 & 7);
  const int wrow1 = ((l15 >> 3) + 2) * H_ + jb8 + (l15 & 7);

  // epilogue identity: one thread per (b, unit)
  const int eb = tid & 63;
  const int eu = tid >> 6;                 // 0..7
  const int ej = jb8 + eu;

  // prefetch gate inputs + c (coalesced over b) while the GEMM runs
  const float* xr = xp + ((size_t)(tl * 4) * H_ + ej) * 64 + eb;
  float xpv0 = xr[0];
  float xpv1 = xr[(size_t)H_ * 64];
  float xpv2 = xr[(size_t)2 * H_ * 64];
  float xpv3 = xr[(size_t)3 * H_ * 64];
  float cv   = cst[ej * B_ + eb];

  fx4 acc[4][2] = {};
  const int kb0 = wv * 128 + koff;
  #pragma unroll
  for (int s = 0; s < 4; ++s){
    const int kb = kb0 + s * 32;
    const size_t wo0 = (size_t)wrow0 * H_ + kb;
    const size_t wo1 = (size_t)wrow1 * H_ + kb;
    s16x8 bh0 = *reinterpret_cast<const s16x8*>(Wh + wo0);
    s16x8 bl0 = *reinterpret_cast<const s16x8*>(Wl + wo0);
    s16x8 bh1 = *reinterpret_cast<const s16x8*>(Wh + wo1);
    s16x8 bl1 = *reinterpret_cast<const s16x8*>(Wl + wo1);
    #pragma unroll
    for (int mt = 0; mt < 4; ++mt){
      const size_t ho = (size_t)(mt * 16 + l15) * H_ + kb;
      s16x8 ah = *reinterpret_cast<const s16x8*>(rh + ho);
      s16x8 al = *reinterpret_cast<const s16x8*>(rl + ho);
      acc[mt][0] = mfma(ah, bh0, acc[mt][0]);
      acc[mt][0] = mfma(ah, bl0, acc[mt][0]);
      acc[mt][0] = mfma(al, bh0, acc[mt][0]);
      acc[mt][1] = mfma(ah, bh1, acc[mt][1]);
      acc[mt][1] = mfma(ah, bl1, acc[mt][1]);
      acc[mt][1] = mfma(al, bh1, acc[mt][1]);
    }
  }

  // ---- phase A: reduce ct0 (i,f) ----
  #pragma unroll
  for (int mt = 0; mt < 4; ++mt)
    #pragma unroll
    for (int r = 0; r < 4; ++r)
      red[(mt * 16 + lhi * 4 + r) * 129 + l15 * 8 + wv] = acc[mt][0][r];
  __syncthreads();
  float i_s, f_s;
  {
    const float* ri = red + eb * 129 + eu * 8;        // c = eu (gate i)
    const float* rf = red + eb * 129 + (8 + eu) * 8;  // c = 8+eu (gate f)
    i_s = ((ri[0] + ri[1]) + (ri[2] + ri[3])) + ((ri[4] + ri[5]) + (ri[6] + ri[7]));
    f_s = ((rf[0] + rf[1]) + (rf[2] + rf[3])) + ((rf[4] + rf[5]) + (rf[6] + rf[7]));
  }
  __syncthreads();

  // ---- phase B: reduce ct1 (g,o) ----
  #pragma unroll
  for (int mt = 0; mt < 4; ++mt)
    #pragma unroll
    for (int r = 0; r < 4; ++r)
      red[(mt * 16 + lhi * 4 + r) * 129 + l15 * 8 + wv] = acc[mt][1][r];
  __syncthreads();
  float g_s, o_s;
  {
    const float* rg = red + eb * 129 + eu * 8;
    const float* ro = red + eb * 129 + (8 + eu) * 8;
    g_s = ((rg[0] + rg[1]) + (rg[2] + rg[3])) + ((rg[4] + rg[5]) + (rg[6] + rg[7]));
    o_s = ((ro[0] + ro[1]) + (ro[2] + ro[3])) + ((ro[4] + ro[5]) + (ro[6] + ro[7]));
  }

  // ---- LSTM update: all 512 threads, one (b, unit) each ----
  float iv = sigm (i_s + xpv0);
  float fv = sigm (f_s + xpv1);
  float gv = tanh_(g_s + xpv2);
  float ov = sigm (o_s + xpv3);
  float cn = fv * cv + iv * gv;
  float hv = ov * tanh_(cn);
  cst[ej * B_ + eb] = cn;
  u16 hh = f2bf(hv);
  u16 hl = f2bf(hv - bf2f(hh));
  nh[eb * H_ + ej] = hh;
  nl[eb * H_ + ej] = hl;
  const size_t ai = ((size_t)eb * TC_ + tl) * H_ + ej;
  hah[ai] = hh;
  hal[ai] = hl;
}

// ---------------- host launch ----------------
extern "C" void kernel_launch(void* const* d_in, const int* in_sizes, int n_in,
                              void* d_out, int out_size, void* d_ws, size_t ws_size,
                              hipStream_t stream)
{
  const float* x    = (const float*)d_in[0];
  const float* Wih1 = (const float*)d_in[1];
  const float* Whh1 = (const float*)d_in[2];
  const float* bih1 = (const float*)d_in[3];
  const float* bhh1 = (const float*)d_in[4];
  const float* Wih2 = (const float*)d_in[5];
  const float* Whh2 = (const float*)d_in[6];
  const float* bih2 = (const float*)d_in[7];
  const float* bhh2 = (const float*)d_in[8];
  const float* fcW  = (const float*)d_in[9];
  const float* fcb  = (const float*)d_in[10];
  float* out = (float*)d_out;
  (void)in_sizes; (void)n_in; (void)out_size; (void)ws_size;

  char* base = (char*)d_ws;
  size_t off = 0;
  auto alloc = [&](size_t bytes) -> void* {
    void* p = base + off;
    off = (off + bytes + 255) & ~(size_t)255;
    return p;
  };
  u16* Wih1_hi = (u16*)alloc((size_t)G4_ * I_ * 2);
  u16* Wih1_lo = (u16*)alloc((size_t)G4_ * I_ * 2);
  u16* Whh1_hi = (u16*)alloc((size_t)G4_ * H_ * 2);
  u16* Whh1_lo = (u16*)alloc((size_t)G4_ * H_ * 2);
  u16* Wih2_hi = (u16*)alloc((size_t)G4_ * H_ * 2);
  u16* Wih2_lo = (u16*)alloc((size_t)G4_ * H_ * 2);
  u16* Whh2_hi = (u16*)alloc((size_t)G4_ * H_ * 2);
  u16* Whh2_lo = (u16*)alloc((size_t)G4_ * H_ * 2);
  u16* fcW_hi  = (u16*)alloc((size_t)O_ * H_ * 2);
  u16* fcW_lo  = (u16*)alloc((size_t)O_ * H_ * 2);
  float* bsum1 = (float*)alloc((size_t)G4_ * 4);
  float* bsum2 = (float*)alloc((size_t)G4_ * 4);
  float* cst1  = (float*)alloc((size_t)B_ * H_ * 4);
  float* cst2  = (float*)alloc((size_t)B_ * H_ * 4);
  u16* h1b0h = (u16*)alloc((size_t)B_ * H_ * 2);
  u16* h1b0l = (u16*)alloc((size_t)B_ * H_ * 2);
  u16* h1b1h = (u16*)alloc((size_t)B_ * H_ * 2);
  u16* h1b1l = (u16*)alloc((size_t)B_ * H_ * 2);
  u16* h2b0h = (u16*)alloc((size_t)B_ * H_ * 2);
  u16* h2b0l = (u16*)alloc((size_t)B_ * H_ * 2);
  u16* h2b1h = (u16*)alloc((size_t)B_ * H_ * 2);
  u16* h2b1l = (u16*)alloc((size_t)B_ * H_ * 2);
  u16* h1s_hi = (u16*)alloc((size_t)B_ * TC_ * H_ * 2);
  u16* h1s_lo = (u16*)alloc((size_t)B_ * TC_ * H_ * 2);
  u16* h2s_hi = (u16*)alloc((size_t)B_ * TC_ * H_ * 2);
  u16* h2s_lo = (u16*)alloc((size_t)B_ * TC_ * H_ * 2);
  float* xp1  = (float*)alloc((size_t)TC_ * G4_ * B_ * 4);  // 64 MB, [tl][g][j][b]
  float* xp2  = (float*)alloc((size_t)TC_ * G4_ * B_ * 4);  // 64 MB

  u16* h1h[2] = { h1b0h, h1b1h };
  u16* h1l[2] = { h1b0l, h1b1l };
  u16* h2h[2] = { h2b0h, h2b1h };
  u16* h2l[2] = { h2b0l, h2b1l };

  // ---- prep ----
  cvt_hilo<<<512, 256, 0, stream>>>(Wih1, Wih1_hi, Wih1_lo, G4_ * I_ / 4);
  cvt_hilo<<<512, 256, 0, stream>>>(Whh1, Whh1_hi, Whh1_lo, G4_ * H_ / 4);
  cvt_hilo<<<512, 256, 0, stream>>>(Wih2, Wih2_hi, Wih2_lo, G4_ * H_ / 4);
  cvt_hilo<<<512, 256, 0, stream>>>(Whh2, Whh2_hi, Whh2_lo, G4_ * H_ / 4);
  cvt_hilo<<<256, 256, 0, stream>>>(fcW,  fcW_hi,  fcW_lo,  O_ * H_ / 4);
  vadd<<<16, 256, 0, stream>>>(bih1, bhh1, bsum1, G4_);
  vadd<<<16, 256, 0, stream>>>(bih2, bhh2, bsum2, G4_);

  hipMemsetAsync(cst1,  0, (size_t)B_ * H_ * 4, stream);
  hipMemsetAsync(cst2,  0, (size_t)B_ * H_ * 4, stream);
  hipMemsetAsync(h1b0h, 0, (size_t)B_ * H_ * 2, stream);
  hipMemsetAsync(h1b0l, 0, (size_t)B_ * H_ * 2, stream);
  hipMemsetAsync(h2b0h, 0, (size_t)B_ * H_ * 2, stream);
  hipMemsetAsync(h2b0l, 0, (size_t)B_ * H_ * 2, stream);

  const dim3 gX(32, 64);   // M=4096/128, N=4096/64
  const dim3 gF(32, 8);    // M=4096/128, N=512/64

  // xp1 for chunk 0
  gemmX<I_, 0, 0><<<gX, 256, 0, stream>>>(
      x, nullptr, nullptr, Wih1_hi, Wih1_lo, bsum1, xp1, G4_, 0);

  for (int c = 0; c <= NCH; ++c){
    const int mode = ((c < NCH) ? 1 : 0) | ((c >= 1) ? 2 : 0);
    const int nwg  = (mode == 3) ? 256 : 128;
    for (int tl = 0; tl < TC_; ++tl){
      const int par = tl & 1;
      lstm_step_dual<<<nwg, 512, 0, stream>>>(mode, tl,
          Whh1_hi, Whh1_lo, xp1, cst1,
          h1h[par], h1l[par], h1h[par ^ 1], h1l[par ^ 1], h1s_hi, h1s_lo,
          Whh2_hi, Whh2_lo, xp2, cst2,
          h2h[par], h2l[par], h2h[par ^ 1], h2l[par ^ 1], h2s_hi, h2s_lo);
    }
    if (c < NCH)
      gemmX<H_, 1, 0><<<gX, 256, 0, stream>>>(
          nullptr, h1s_hi, h1s_lo, Wih2_hi, Wih2_lo, bsum2, xp2, G4_, 0);
    if (c + 1 < NCH)
      gemmX<I_, 0, 0><<<gX, 256, 0, stream>>>(
          x, nullptr, nullptr, Wih1_hi, Wih1_lo, bsum1, xp1, G4_, (c + 1) * TC_);
    if (c >= 1)
      gemmX<H_, 1, 1><<<gF, 256, 0, stream>>>(
          nullptr, h2s_hi, h2s_lo, fcW_hi, fcW_lo, fcb, out, O_, (c - 1) * TC_);
  }
}